// Round 4
// baseline (753.041 us; speedup 1.0000x reference)
//
#include <hip/hip_runtime.h>

#define HF   208
#define WF   208
#define D_C  256
#define LC   10816
#define NPTS 5000
#define HW   (HF*WF)                    // 43264
#define INV_S 0.08838834764831845f      // 1/sqrt(128)
#define PAD  136                        // bf16 row pad for sV

// ptg block-role partition (fast path)
#define G_BLOCKS   1250                 // 8 rows each -> 10000 rows
#define PREP_BLOCKS 641
#define TR_PER_TB  1352                 // 43264 / 32
#define TR_BLOCKS  (4*TR_PER_TB)        // 5408
#define PTG_GRID   (G_BLOCKS + PREP_BLOCKS + TR_BLOCKS)   // 7299

typedef __bf16 bf16_t;
typedef __bf16 bf16x8 __attribute__((ext_vector_type(8)));
typedef float  f32x4  __attribute__((ext_vector_type(4)));

// Workspace layout:
//   +0        float ctxs[512]       raw channel sums (atomic), scaled in main
//   +4096     float bias_all[128]   full bias (fallback path only)
//   +8192     bf16  A_swz[3*16384]  B-fragment-swizzled fused mats
//   +106496   bf16  DmB[32][128][8] down_proj@merge fused, t-blocked (fallback)
//   +172032   bf16  ftr[2][2][HW][128]   44.30 MB transposed features
//   +FTR_END  float g[10000][128]        5.12 MB  fc@dp@mg2 + full bias
#define FTR_OFF   172032
#define FTR_BYTES ((size_t)2*2*HW*128*2)
#define G_OFF     (FTR_OFF + FTR_BYTES)
#define G_BYTES   ((size_t)2*NPTS*128*4)

// ---------------------------------------------------------------------------
// Kernel A (fused, one dispatch; role order = [g][prep][transpose] so the
// latency-bound g/prep blocks launch first and overlap the BW-bound
// transpose stream instead of trailing it).
//   g:        8 output rows per block, g[r] = ((fc_r@dp_w)+dp_b)@mg_w2
//             + mg_b + corr_b@mg_w1   (original weights -> independent)
//   prep:     fused-weight precompute (A_swz, DmB, bias_all)
//   transpose:(B,C,H,W) f32 -> (t,b,HW,C) bf16, 32-row tiles (17KB LDS ->
//             8 blocks/CU) + channel sums
// Fallback dispatch uses grid=641 -> all blocks are prep.
// ---------------------------------------------------------------------------
__global__ __launch_bounds__(256) void ptg_kernel(
    const float* __restrict__ f0, const float* __restrict__ f1,
    const float* __restrict__ fc0, const float* __restrict__ fc1,
    const float* __restrict__ corr_w, const float* __restrict__ corr_b,
    const float* __restrict__ dp_w,   const float* __restrict__ dp_b,
    const float* __restrict__ mg_w,   const float* __restrict__ mg_b,
    const int* __restrict__ b_ids, const int* __restrict__ i_ids,
    const int* __restrict__ j_ids,
    bf16_t* __restrict__ A_swz, bf16_t* __restrict__ DmB,
    float* __restrict__ bias_all,
    bf16_t* __restrict__ ftr, float* __restrict__ ctxs,
    float* __restrict__ g) {
  __shared__ union {
    struct { float tile[32][129]; float cred[128]; } tr;  // 17024 B (transpose)
    float s_src[8][256];                                  //  8192 B (g part)
  } sm;
  int bid = blockIdx.x;
  int tid = threadIdx.x;

  int prep_id = -1;
  if (gridDim.x == 641) {
    prep_id = bid;                       // fallback: prep-only dispatch
  } else if (bid >= G_BLOCKS && bid < G_BLOCKS + PREP_BLOCKS) {
    prep_id = bid - G_BLOCKS;
  }

  if (prep_id >= 0) {                  // ---- prep part (128 active threads)
    if (tid >= 128) return;
    int c = tid;
    if (prep_id < 384) {
      int mat = prep_id >> 7, r = prep_id & 127;
      float acc = 0.f;
      for (int t = 0; t < 128; ++t)
        acc += corr_w[(mat * 128 + r) * 128 + t] * mg_w[t * 128 + c];
      if (mat == 0) acc *= INV_S;
      // B-fragment swizzle (mfma_f32_16x16x32_bf16): (k=r,n=c) ->
      // lane=((k&31)>>3)*16+(n&15), j=k&7, tiles (nt=n>>4, ks=k>>5)
      int ks = r >> 5, quad = (r & 31) >> 3, jj = r & 7;
      int nt = c >> 4, lr = c & 15;
      A_swz[mat * 16384 + (((nt * 4 + ks) * 64) + quad * 16 + lr) * 8 + jj] = (bf16_t)acc;
    } else if (prep_id < 640) {
      int r = prep_id - 384;
      float acc = 0.f;
      for (int t = 0; t < 128; ++t)
        acc += dp_w[r * 128 + t] * mg_w[(128 + t) * 128 + c];
      DmB[(((r >> 3) * 128) + c) * 8 + (r & 7)] = (bf16_t)acc;   // fallback only
    } else {
      float acc = mg_b[c];
      for (int t = 0; t < 128; ++t) {
        acc += corr_b[t] * mg_w[t * 128 + c];
        acc += dp_b[t]   * mg_w[(128 + t) * 128 + c];
      }
      bias_all[c] = acc;               // fallback only
    }
    return;
  }

  if (bid < G_BLOCKS) {                // ---- g part (all f32, orig weights)
    int r0 = bid * 8;
    // stage 8 fc rows (1KB coalesced each)
    for (int k = 0; k < 8; ++k) {
      int r = r0 + k;
      const float* src;
      int b, idx;
      if (r < NPTS) { b = b_ids[r]; idx = i_ids[r]; src = fc0; }
      else          { b = b_ids[r - NPTS]; idx = j_ids[r - NPTS]; src = fc1; }
      sm.s_src[k][tid] = src[((size_t)b * LC + idx) * D_C + tid];
    }
    __syncthreads();
    int col = tid & 127, half = tid >> 7;   // this thread: rows half*4..half*4+3
    float h[4];
    {
      float db = dp_b[col];
#pragma unroll
      for (int r4 = 0; r4 < 4; ++r4) h[r4] = db;
      for (int t = 0; t < 256; t += 4) {
        f32x4 wv;
#pragma unroll
        for (int k = 0; k < 4; ++k) wv[k] = dp_w[(t + k) * 128 + col];
#pragma unroll
        for (int r4 = 0; r4 < 4; ++r4) {
          f32x4 sv = *(const f32x4*)&sm.s_src[half * 4 + r4][t];
          h[r4] += sv[0] * wv[0] + sv[1] * wv[1] + sv[2] * wv[2] + sv[3] * wv[3];
        }
      }
    }
    __syncthreads();
    float* s_h = &sm.s_src[0][0];      // reuse as [8][128]
#pragma unroll
    for (int r4 = 0; r4 < 4; ++r4) s_h[(half * 4 + r4) * 128 + col] = h[r4];
    __syncthreads();
    float acc2[4];
    float mb = mg_b[col];
#pragma unroll
    for (int r4 = 0; r4 < 4; ++r4) acc2[r4] = mb;
    for (int t = 0; t < 128; t += 4) {
      f32x4 wv;
#pragma unroll
      for (int k = 0; k < 4; ++k) wv[k] = mg_w[(128 + t + k) * 128 + col];
#pragma unroll
      for (int r4 = 0; r4 < 4; ++r4) {
        f32x4 sv = *(const f32x4*)&s_h[(half * 4 + r4) * 128 + t];
        acc2[r4] += sv[0] * wv[0] + sv[1] * wv[1] + sv[2] * wv[2] + sv[3] * wv[3];
      }
    }
    // corr-bias column: cp = sum_t corr_b[t] * mg_w1[t][col]
    float cp = 0.f;
    for (int t = 0; t < 128; ++t) cp += corr_b[t] * mg_w[t * 128 + col];
#pragma unroll
    for (int r4 = 0; r4 < 4; ++r4)
      g[(size_t)(r0 + half * 4 + r4) * 128 + col] = acc2[r4] + cp;
    return;
  }

  // ---- transpose part: 32-row tiles ----
  int tbid = bid - (G_BLOCKS + PREP_BLOCKS);   // 0..5407
  int tb = tbid / TR_PER_TB;                   // t*2+b
  int hw0 = (tbid % TR_PER_TB) * 32;
  const float* src = (tb < 2 ? f0 : f1) + (size_t)((tb & 1) * 128) * HW;
  if (tid < 128) sm.tr.cred[tid] = 0.f;
  // read: float4 along w; 8 w-groups x 32 channels per pass, 4 passes
  int w4 = (tid & 7) * 4, cr = tid >> 3;       // cr in 0..31
  for (int c = cr; c < 128; c += 32) {
    f32x4 v = *(const f32x4*)&src[(size_t)c * HW + hw0 + w4];
#pragma unroll
    for (int j = 0; j < 4; ++j) sm.tr.tile[w4 + j][c] = v[j];
  }
  __syncthreads();
  // store: bf16x8 along c, accumulate channel sums on the way
  bf16_t* dst = ftr + ((size_t)tb * HW + hw0) * 128;
  int cb = (tid & 15) * 8;
  float sums8[8] = {0, 0, 0, 0, 0, 0, 0, 0};
  for (int p = (tid >> 4); p < 32; p += 16) {
    bf16x8 v;
#pragma unroll
    for (int j = 0; j < 8; ++j) {
      float x = sm.tr.tile[p][cb + j];
      sums8[j] += x;
      v[j] = (bf16_t)x;
    }
    *(bf16x8*)(dst + (size_t)p * 128 + cb) = v;
  }
  int lane = tid & 63;
#pragma unroll
  for (int j = 0; j < 8; ++j) {
    float s = sums8[j];
    s += __shfl_down(s, 32, 64);
    s += __shfl_down(s, 16, 64);
    if (lane < 16) atomicAdd(&sm.tr.cred[cb + j], s);
  }
  __syncthreads();
  if (tid < 128) atomicAdd(&ctxs[tb * 128 + tid], sm.tr.cred[tid]);
}

// ---------------------------------------------------------------------------
// Kernel B: main — one block per match n. Gather -> MFMA -> LDS-staged
// coalesced nontemporal output (+precomputed g, bias folded into g).
// ---------------------------------------------------------------------------
__global__ __launch_bounds__(256, 6) void main_kernel(
    const bf16_t* __restrict__ ftr,
    const int* __restrict__ b_ids, const int* __restrict__ i_ids,
    const int* __restrict__ j_ids, const int* __restrict__ w0c_p,
    const int* __restrict__ w1c_p, const float* __restrict__ ctxs,
    const bf16_t* __restrict__ A_swz, const float* __restrict__ g,
    float* __restrict__ out) {
  __shared__ __align__(16) union {
    bf16_t sV[3][32][PAD];     // 0: p0*p1, 1: p0*cs1, 2: p1*cs0  (26112 B)
    float  so[2][25 * 128];    // f32 output staging, aliased after MFMA
  } sm;

  int n = blockIdx.x;
  int tid = threadIdx.x;
  int b = b_ids[n], ii = i_ids[n], jj = j_ids[n];
  int w0c = w0c_p[0], w1c = w1c_p[0];
  int x0 = min((ii % w0c) * 2, WF - 1), y0 = min((ii / w0c) * 2, HF - 1);
  int x1 = min((jj % w1c) * 2, WF - 1), y1 = min((jj / w1c) * 2, HF - 1);

  // ---- gather: 8 lanes per patch position (rows 25..31 left stale: their
  //      MFMA output rows are discarded by the row<25 guard) ----
  int grp = tid >> 3, e = tid & 7;
  if (grp < 25) {
    const bf16_t* base0 = ftr + (size_t)b * HW * 128;
    const bf16_t* base1 = ftr + (size_t)(2 + b) * HW * 128;
    int dy = grp / 5 - 2, dx = grp % 5 - 2;
    int ya = y0 + dy, xa = x0 + dx;
    int yb = y1 + dy, xb = x1 + dx;
    bool v0 = (ya >= 0 && ya < HF && xa >= 0 && xa < WF);
    bool v1 = (yb >= 0 && yb < HF && xb >= 0 && xb < WF);
    const bf16_t* r0 = base0 + ((size_t)(v0 ? ya * WF + xa : 0)) * 128;
    const bf16_t* r1 = base1 + ((size_t)(v1 ? yb * WF + xb : 0)) * 128;
    const float ksc = INV_S / (float)HW;   // ctxs holds raw sums
#pragma unroll
    for (int h = 0; h < 2; ++h) {
      int cb = h * 64 + e * 8;
      bf16x8 a0 = *(const bf16x8*)(r0 + cb);
      bf16x8 a1 = *(const bf16x8*)(r1 + cb);
      f32x4 cs0a = *(const f32x4*)&ctxs[b * 128 + cb];
      f32x4 cs0b = *(const f32x4*)&ctxs[b * 128 + cb + 4];
      f32x4 cs1a = *(const f32x4*)&ctxs[256 + b * 128 + cb];
      f32x4 cs1b = *(const f32x4*)&ctxs[256 + b * 128 + cb + 4];
      bf16x8 oP, o1, o2;
#pragma unroll
      for (int j = 0; j < 8; ++j) {
        float p0 = v0 ? (float)a0[j] : 0.f;
        float p1 = v1 ? (float)a1[j] : 0.f;
        float c0f = (j < 4 ? cs0a[j & 3] : cs0b[j & 3]) * ksc;
        float c1f = (j < 4 ? cs1a[j & 3] : cs1b[j & 3]) * ksc;
        oP[j] = (bf16_t)(p0 * p1);
        o1[j] = (bf16_t)(p0 * c1f);
        o2[j] = (bf16_t)(p1 * c0f);
      }
      *(bf16x8*)&sm.sV[0][grp][cb] = oP;
      *(bf16x8*)&sm.sV[1][grp][cb] = o1;
      *(bf16x8*)&sm.sV[2][grp][cb] = o2;
    }
  }
  __syncthreads();

  // ---- MFMA phase ----
  int w = tid >> 6, lane = tid & 63, quad = lane >> 4, lr = lane & 15;
  f32x4 accP[2][2] = {};   // vp@A0 (shared by both outputs)
  f32x4 acc01[2][2] = {};  // v0@A1 + v1@A2  (-> out0)
  f32x4 acc10[2][2] = {};  // v1@A1 + v0@A2  (-> out1)

#pragma unroll
  for (int ks = 0; ks < 4; ++ks) {
    bf16x8 va[2][3];
#pragma unroll
    for (int mt = 0; mt < 2; ++mt)
#pragma unroll
      for (int m = 0; m < 3; ++m)
        va[mt][m] = *(const bf16x8*)&sm.sV[m][mt * 16 + lr][ks * 32 + quad * 8];
    bf16x8 vb[3][2];
#pragma unroll
    for (int m = 0; m < 3; ++m)
#pragma unroll
      for (int ntl = 0; ntl < 2; ++ntl) {
        int nt = w * 2 + ntl;
        vb[m][ntl] = *(const bf16x8*)(A_swz + m * 16384 + (((nt * 4 + ks) * 64) + lane) * 8);
      }
#pragma unroll
    for (int mt = 0; mt < 2; ++mt)
#pragma unroll
      for (int ntl = 0; ntl < 2; ++ntl) {
        accP[mt][ntl]  = __builtin_amdgcn_mfma_f32_16x16x32_bf16(va[mt][0], vb[0][ntl], accP[mt][ntl], 0, 0, 0);
        acc01[mt][ntl] = __builtin_amdgcn_mfma_f32_16x16x32_bf16(va[mt][1], vb[1][ntl], acc01[mt][ntl], 0, 0, 0);
        acc01[mt][ntl] = __builtin_amdgcn_mfma_f32_16x16x32_bf16(va[mt][2], vb[2][ntl], acc01[mt][ntl], 0, 0, 0);
        acc10[mt][ntl] = __builtin_amdgcn_mfma_f32_16x16x32_bf16(va[mt][2], vb[1][ntl], acc10[mt][ntl], 0, 0, 0);
        acc10[mt][ntl] = __builtin_amdgcn_mfma_f32_16x16x32_bf16(va[mt][1], vb[2][ntl], acc10[mt][ntl], 0, 0, 0);
      }
  }
  __syncthreads();   // everyone done reading sV before aliasing as so

  // ---- stage C tiles to LDS (C/D: col=lane&15(+tiles), row=quad*4+reg) ----
#pragma unroll
  for (int ntl = 0; ntl < 2; ++ntl) {
    int col = w * 32 + ntl * 16 + lr;
#pragma unroll
    for (int mt = 0; mt < 2; ++mt)
#pragma unroll
      for (int rg = 0; rg < 4; ++rg) {
        int row = mt * 16 + quad * 4 + rg;
        if (row < 25) {
          sm.so[0][row * 128 + col] = accP[mt][ntl][rg] + acc01[mt][ntl][rg];
          sm.so[1][row * 128 + col] = accP[mt][ntl][rg] + acc10[mt][ntl][rg];
        }
      }
  }
  __syncthreads();

  // ---- coalesced nontemporal write-out, adding g (bias already folded) ----
  float* o0 = out + (size_t)n * 3200;
  float* o1 = out + (size_t)NPTS * 3200 + (size_t)n * 3200;
  const float* g0 = g + (size_t)n * 128;
  const float* g1 = g + (size_t)(NPTS + n) * 128;
  for (int i = tid; i < 800; i += 256) {
    int f = i * 4, c = f & 127;
    f32x4 gv0 = *(const f32x4*)(g0 + c);
    f32x4 gv1 = *(const f32x4*)(g1 + c);
    f32x4 v0 = *(const f32x4*)&sm.so[0][f];
    f32x4 v1 = *(const f32x4*)&sm.so[1][f];
    __builtin_nontemporal_store(v0 + gv0, (f32x4*)(o0 + f));
    __builtin_nontemporal_store(v1 + gv1, (f32x4*)(o1 + f));
  }
}

// ---------------------------------------------------------------------------
// Fallback (ws too small for ftr+g): direct f32 gather + fused fc dot.
// ---------------------------------------------------------------------------
__global__ __launch_bounds__(256) void ctx_mean_f32_kernel(
    const float* __restrict__ f0, const float* __restrict__ f1,
    float* __restrict__ ctxs) {
  int id = blockIdx.x;
  const float* src = (id < 256 ? f0 : f1) + (size_t)(id & 255) * HW;
  float s = 0.f;
  for (int i = threadIdx.x; i < HW; i += 256) s += src[i];
  for (int off = 32; off > 0; off >>= 1) s += __shfl_down(s, off, 64);
  __shared__ float part[4];
  if ((threadIdx.x & 63) == 0) part[threadIdx.x >> 6] = s;
  __syncthreads();
  if (threadIdx.x == 0) ctxs[id] = part[0] + part[1] + part[2] + part[3];
}

__global__ __launch_bounds__(256, 4) void main_fallback_kernel(
    const float* __restrict__ f0, const float* __restrict__ f1,
    const float* __restrict__ fc0, const float* __restrict__ fc1,
    const int* __restrict__ b_ids, const int* __restrict__ i_ids,
    const int* __restrict__ j_ids, const int* __restrict__ w0c_p,
    const int* __restrict__ w1c_p, const float* __restrict__ ctxs,
    const float* __restrict__ bias_all, const bf16_t* __restrict__ A_swz,
    const bf16_t* __restrict__ DmB, float* __restrict__ out) {
  __shared__ __align__(16) bf16_t sV[3][32][PAD];
  __shared__ float sg[2][128];
  int n = blockIdx.x;
  int tid = threadIdx.x;
  int b = b_ids[n], ii = i_ids[n], jj = j_ids[n];
  int w0c = w0c_p[0], w1c = w1c_p[0];
  int x0 = min((ii % w0c) * 2, WF - 1), y0 = min((ii / w0c) * 2, HF - 1);
  int x1 = min((jj % w1c) * 2, WF - 1), y1 = min((jj / w1c) * 2, HF - 1);
  const float ksc = INV_S / (float)HW;
  int c = tid & 127, kh = tid >> 7;
  float cs0 = ctxs[b * 128 + c] * ksc;
  float cs1 = ctxs[256 + b * 128 + c] * ksc;
  const float* f0b = f0 + (size_t)(b * 128 + c) * HW;
  const float* f1b = f1 + (size_t)(b * 128 + c) * HW;
  for (int k = kh; k < 32; k += 2) {
    float p0 = 0.f, p1 = 0.f;
    if (k < 25) {
      int dy = k / 5 - 2, dx = k % 5 - 2;
      int ya = y0 + dy, xa = x0 + dx;
      if (ya >= 0 && ya < HF && xa >= 0 && xa < WF) p0 = f0b[ya * WF + xa];
      int yb = y1 + dy, xb = x1 + dx;
      if (yb >= 0 && yb < HF && xb >= 0 && xb < WF) p1 = f1b[yb * WF + xb];
    }
    sV[0][k][c] = (bf16_t)(p0 * p1);
    sV[1][k][c] = (bf16_t)(p0 * cs1);
    sV[2][k][c] = (bf16_t)(p1 * cs0);
  }
  {
    int h = tid >> 7, col = tid & 127;
    const float* fcrow = h ? fc1 + ((size_t)b * LC + jj) * D_C
                           : fc0 + ((size_t)b * LC + ii) * D_C;
    const bf16_t* dbase = DmB + col * 8;
    float p0 = 0.f, p1 = 0.f, p2 = 0.f, p3 = 0.f;
#pragma unroll 4
    for (int t8 = 0; t8 < 32; ++t8) {
      bf16x8 d  = *(const bf16x8*)(dbase + t8 * 1024);
      f32x4  fa = *(const f32x4*)(fcrow + t8 * 8);
      f32x4  fb = *(const f32x4*)(fcrow + t8 * 8 + 4);
      p0 += fa[0] * (float)d[0] + fb[0] * (float)d[4];
      p1 += fa[1] * (float)d[1] + fb[1] * (float)d[5];
      p2 += fa[2] * (float)d[2] + fb[2] * (float)d[6];
      p3 += fa[3] * (float)d[3] + fb[3] * (float)d[7];
    }
    sg[h][col] = ((p0 + p1) + (p2 + p3));
  }
  __syncthreads();
  int w = tid >> 6, lane = tid & 63, quad = lane >> 4, lr = lane & 15;
  f32x4 accP[2][2] = {}, acc01[2][2] = {}, acc10[2][2] = {};
#pragma unroll
  for (int ks = 0; ks < 4; ++ks) {
    bf16x8 va[2][3];
#pragma unroll
    for (int mt = 0; mt < 2; ++mt)
#pragma unroll
      for (int m = 0; m < 3; ++m)
        va[mt][m] = *(const bf16x8*)&sV[m][mt * 16 + lr][ks * 32 + quad * 8];
    bf16x8 vb[3][2];
#pragma unroll
    for (int m = 0; m < 3; ++m)
#pragma unroll
      for (int ntl = 0; ntl < 2; ++ntl) {
        int nt = w * 2 + ntl;
        vb[m][ntl] = *(const bf16x8*)(A_swz + m * 16384 + (((nt * 4 + ks) * 64) + lane) * 8);
      }
#pragma unroll
    for (int mt = 0; mt < 2; ++mt)
#pragma unroll
      for (int ntl = 0; ntl < 2; ++ntl) {
        accP[mt][ntl]  = __builtin_amdgcn_mfma_f32_16x16x32_bf16(va[mt][0], vb[0][ntl], accP[mt][ntl], 0, 0, 0);
        acc01[mt][ntl] = __builtin_amdgcn_mfma_f32_16x16x32_bf16(va[mt][1], vb[1][ntl], acc01[mt][ntl], 0, 0, 0);
        acc01[mt][ntl] = __builtin_amdgcn_mfma_f32_16x16x32_bf16(va[mt][2], vb[2][ntl], acc01[mt][ntl], 0, 0, 0);
        acc10[mt][ntl] = __builtin_amdgcn_mfma_f32_16x16x32_bf16(va[mt][2], vb[1][ntl], acc10[mt][ntl], 0, 0, 0);
        acc10[mt][ntl] = __builtin_amdgcn_mfma_f32_16x16x32_bf16(va[mt][1], vb[2][ntl], acc10[mt][ntl], 0, 0, 0);
      }
  }
#pragma unroll
  for (int ntl = 0; ntl < 2; ++ntl) {
    int col = w * 32 + ntl * 16 + lr;
    float bg = bias_all[col];
    float gg0 = sg[0][col] + bg, gg1 = sg[1][col] + bg;
#pragma unroll
    for (int mt = 0; mt < 2; ++mt)
#pragma unroll
      for (int rg = 0; rg < 4; ++rg) {
        int row = mt * 16 + quad * 4 + rg;
        if (row < 25) {
          size_t o = ((size_t)n * 25 + row) * 128 + col;
          out[o] = accP[mt][ntl][rg] + acc01[mt][ntl][rg] + gg0;
          out[(size_t)NPTS * 25 * 128 + o] = accP[mt][ntl][rg] + acc10[mt][ntl][rg] + gg1;
        }
      }
  }
}

// ---------------------------------------------------------------------------
extern "C" void kernel_launch(void* const* d_in, const int* in_sizes, int n_in,
                              void* d_out, int out_size, void* d_ws, size_t ws_size,
                              hipStream_t stream) {
  const float* f0     = (const float*)d_in[0];
  const float* f1     = (const float*)d_in[1];
  const float* fc0    = (const float*)d_in[2];
  const float* fc1    = (const float*)d_in[3];
  const float* corr_w = (const float*)d_in[4];
  const float* corr_b = (const float*)d_in[5];
  const float* dp_w   = (const float*)d_in[6];
  const float* dp_b   = (const float*)d_in[7];
  const float* mg_w   = (const float*)d_in[8];
  const float* mg_b   = (const float*)d_in[9];
  const int* b_ids    = (const int*)d_in[10];
  const int* i_ids    = (const int*)d_in[11];
  const int* j_ids    = (const int*)d_in[12];
  const int* w0c      = (const int*)d_in[13];
  const int* w1c      = (const int*)d_in[14];

  char* ws = (char*)d_ws;
  float*  ctxs     = (float*)(ws);
  float*  bias_all = (float*)(ws + 4096);
  bf16_t* A_swz    = (bf16_t*)(ws + 8192);
  bf16_t* DmB      = (bf16_t*)(ws + 106496);
  bf16_t* ftr      = (bf16_t*)(ws + FTR_OFF);
  float*  g        = (float*)(ws + G_OFF);
  int fast = (ws_size >= G_OFF + G_BYTES) ? 1 : 0;

  if (fast) {
    hipMemsetAsync(ctxs, 0, 2048, stream);
    // g (1250) + prep (641) + transpose (5408) fused: one dispatch, all
    // three parts independent (g uses original weights, not prep output).
    ptg_kernel<<<PTG_GRID, 256, 0, stream>>>(
        f0, f1, fc0, fc1, corr_w, corr_b, dp_w, dp_b, mg_w, mg_b,
        b_ids, i_ids, j_ids, A_swz, DmB, bias_all, ftr, ctxs, g);
    main_kernel<<<NPTS, 256, 0, stream>>>(ftr, b_ids, i_ids, j_ids, w0c, w1c,
                                          ctxs, A_swz, g, (float*)d_out);
  } else {
    // prep-only dispatch (grid==641 -> every block runs the prep role)
    ptg_kernel<<<641, 256, 0, stream>>>(
        f0, f1, fc0, fc1, corr_w, corr_b, dp_w, dp_b, mg_w, mg_b,
        b_ids, i_ids, j_ids, A_swz, DmB, bias_all, ftr, ctxs, g);
    ctx_mean_f32_kernel<<<512, 256, 0, stream>>>(f0, f1, ctxs);
    main_fallback_kernel<<<NPTS, 256, 0, stream>>>(f0, f1, fc0, fc1, b_ids,
                                                   i_ids, j_ids, w0c, w1c, ctxs,
                                                   bias_all, A_swz, DmB,
                                                   (float*)d_out);
  }
}

// Round 5
// 330.014 us; speedup vs baseline: 2.2818x; 2.2818x over previous
//
#include <hip/hip_runtime.h>

#define HF   208
#define WF   208
#define D_C  256
#define LC   10816
#define NPTS 5000
#define HW   (HF*WF)                    // 43264
#define INV_S 0.08838834764831845f      // 1/sqrt(128)
#define PAD  136                        // bf16 row pad for sV

// ptg block-role partition (fast path): [g][prep][transpose]
#define G_BLOCKS    625                 // 16 rows each -> 10000 rows
#define PREP_BLOCKS 641
#define TR_BLOCKS   2704                // 4 tb * 676 tiles of 64 rows
#define PTG_GRID    (G_BLOCKS + PREP_BLOCKS + TR_BLOCKS)   // 3970

typedef __bf16 bf16_t;
typedef __bf16 bf16x8 __attribute__((ext_vector_type(8)));
typedef float  f32x4  __attribute__((ext_vector_type(4)));

// Workspace layout:
//   +0        float ctxs[512]       raw channel sums (atomic), scaled in main
//   +4096     float bias_all[128]   full bias (fallback path only)
//   +8192     bf16  A_swz[3*16384]  B-fragment-swizzled fused mats
//   +106496   bf16  DmB[32][128][8] down_proj@merge fused, t-blocked (fallback)
//   +172032   bf16  ftr[2][2][HW][128]   44.30 MB transposed features
//   +FTR_END  float g[10000][128]        5.12 MB  fc@dp@mg2 + full bias
#define FTR_OFF   172032
#define FTR_BYTES ((size_t)2*2*HW*128*2)
#define G_OFF     (FTR_OFF + FTR_BYTES)
#define G_BYTES   ((size_t)2*NPTS*128*4)

// ---------------------------------------------------------------------------
// Kernel A (fused, one dispatch; role order = [g][prep][transpose] so the
// latency-bound g/prep blocks launch first and overlap the BW-bound
// transpose stream instead of trailing it).
//   g:        16 output rows per block, g[r] = ((fc_r@dp_w)+dp_b)@mg_w2
//             + mg_b + corr_b@mg_w1   (original weights -> independent)
//   prep:     fused-weight precompute (A_swz, DmB, bias_all)
//   transpose:(B,C,H,W) f32 -> (t,b,HW,C) bf16 + channel sums.
//             bf16 LDS tile (17.9KB union) -> 8 blocks/CU. Sums computed
//             in-register from f32 BEFORE bf16 conversion (exact).
// __launch_bounds__(256,8): VGPR cap 64 (round-3 natural use was 56).
// Guards against the round-4 256-VGPR/spill codegen blowup.
// Fallback dispatch uses grid=641 -> all blocks are prep.
// ---------------------------------------------------------------------------
__global__ __launch_bounds__(256, 8) void ptg_kernel(
    const float* __restrict__ f0, const float* __restrict__ f1,
    const float* __restrict__ fc0, const float* __restrict__ fc1,
    const float* __restrict__ corr_w, const float* __restrict__ corr_b,
    const float* __restrict__ dp_w,   const float* __restrict__ dp_b,
    const float* __restrict__ mg_w,   const float* __restrict__ mg_b,
    const int* __restrict__ b_ids, const int* __restrict__ i_ids,
    const int* __restrict__ j_ids,
    bf16_t* __restrict__ A_swz, bf16_t* __restrict__ DmB,
    float* __restrict__ bias_all,
    bf16_t* __restrict__ ftr, float* __restrict__ ctxs,
    float* __restrict__ g) {
  __shared__ __align__(16) union {
    struct { bf16_t tile[64][136]; float cred[128]; } tr;  // 17920 B
    float s_src[16][256];                                  // 16384 B (g part)
  } sm;
  int bid = blockIdx.x;
  int tid = threadIdx.x;

  int prep_id = -1;
  if (gridDim.x == 641) {
    prep_id = bid;                       // fallback: prep-only dispatch
  } else if (bid >= G_BLOCKS && bid < G_BLOCKS + PREP_BLOCKS) {
    prep_id = bid - G_BLOCKS;
  }

  if (prep_id >= 0) {                  // ---- prep part (128 active threads)
    if (tid >= 128) return;
    int c = tid;
    if (prep_id < 384) {
      int mat = prep_id >> 7, r = prep_id & 127;
      float acc = 0.f;
      for (int t = 0; t < 128; ++t)
        acc += corr_w[(mat * 128 + r) * 128 + t] * mg_w[t * 128 + c];
      if (mat == 0) acc *= INV_S;
      // B-fragment swizzle (mfma_f32_16x16x32_bf16): (k=r,n=c) ->
      // lane=((k&31)>>3)*16+(n&15), j=k&7, tiles (nt=n>>4, ks=k>>5)
      int ks = r >> 5, quad = (r & 31) >> 3, jj = r & 7;
      int nt = c >> 4, lr = c & 15;
      A_swz[mat * 16384 + (((nt * 4 + ks) * 64) + quad * 16 + lr) * 8 + jj] = (bf16_t)acc;
    } else if (prep_id < 640) {
      int r = prep_id - 384;
      float acc = 0.f;
      for (int t = 0; t < 128; ++t)
        acc += dp_w[r * 128 + t] * mg_w[(128 + t) * 128 + c];
      DmB[(((r >> 3) * 128) + c) * 8 + (r & 7)] = (bf16_t)acc;   // fallback only
    } else {
      float acc = mg_b[c];
      for (int t = 0; t < 128; ++t) {
        acc += corr_b[t] * mg_w[t * 128 + c];
        acc += dp_b[t]   * mg_w[(128 + t) * 128 + c];
      }
      bias_all[c] = acc;               // fallback only
    }
    return;
  }

  if (bid < G_BLOCKS) {                // ---- g part (all f32, orig weights)
    int r0 = bid * 16;
    for (int u = tid; u < 16 * 256; u += 256) {
      int rr = u >> 8, t = u & 255;
      int r = r0 + rr;
      const float* src;
      int b, idx;
      if (r < NPTS) { b = b_ids[r]; idx = i_ids[r]; src = fc0; }
      else          { b = b_ids[r - NPTS]; idx = j_ids[r - NPTS]; src = fc1; }
      sm.s_src[rr][t] = src[((size_t)b * LC + idx) * D_C + t];
    }
    __syncthreads();
    int col = tid & 127, half = tid >> 7;   // this thread: rows half*8..half*8+7
    float h[8];
    {
      float db = dp_b[col];
#pragma unroll
      for (int r8 = 0; r8 < 8; ++r8) h[r8] = db;
      for (int t = 0; t < 256; t += 4) {
        f32x4 wv;
#pragma unroll
        for (int k = 0; k < 4; ++k) wv[k] = dp_w[(t + k) * 128 + col];
#pragma unroll
        for (int r8 = 0; r8 < 8; ++r8) {
          f32x4 sv = *(const f32x4*)&sm.s_src[half * 8 + r8][t];
          h[r8] += sv[0] * wv[0] + sv[1] * wv[1] + sv[2] * wv[2] + sv[3] * wv[3];
        }
      }
    }
    __syncthreads();
    float* s_h = &sm.s_src[0][0];      // reuse as [16][128]
#pragma unroll
    for (int r8 = 0; r8 < 8; ++r8) s_h[(half * 8 + r8) * 128 + col] = h[r8];
    __syncthreads();
    float acc2[8];
    float mb = mg_b[col];
#pragma unroll
    for (int r8 = 0; r8 < 8; ++r8) acc2[r8] = mb;
    for (int t = 0; t < 128; t += 4) {
      f32x4 wv;
#pragma unroll
      for (int k = 0; k < 4; ++k) wv[k] = mg_w[(128 + t + k) * 128 + col];
#pragma unroll
      for (int r8 = 0; r8 < 8; ++r8) {
        f32x4 sv = *(const f32x4*)&s_h[(half * 8 + r8) * 128 + t];
        acc2[r8] += sv[0] * wv[0] + sv[1] * wv[1] + sv[2] * wv[2] + sv[3] * wv[3];
      }
    }
    // corr-bias column: cp = sum_t corr_b[t] * mg_w1[t][col]
    float cp = 0.f;
    for (int t = 0; t < 128; ++t) cp += corr_b[t] * mg_w[t * 128 + col];
#pragma unroll
    for (int r8 = 0; r8 < 8; ++r8)
      g[(size_t)(r0 + half * 8 + r8) * 128 + col] = acc2[r8] + cp;
    return;
  }

  // ---- transpose part: 64-row tiles, bf16 LDS ----
  int tbid = bid - (G_BLOCKS + PREP_BLOCKS);   // 0..2703
  int tb = tbid / 676;                         // t*2+b
  int hw0 = (tbid % 676) * 64;
  const float* src = (tb < 2 ? f0 : f1) + (size_t)((tb & 1) * 128) * HW;
  int wg = tid & 15, cr = tid >> 4;            // wg: w-group, cr: 0..15
  int w4 = wg * 4;
  // read: f32x4 along w; convert to bf16 into tile; channel sums from f32
  float csum[8];
#pragma unroll
  for (int k = 0; k < 8; ++k) {
    int c = cr + k * 16;
    f32x4 v = *(const f32x4*)&src[(size_t)c * HW + hw0 + w4];
    csum[k] = (v[0] + v[1]) + (v[2] + v[3]);
#pragma unroll
    for (int j = 0; j < 4; ++j) sm.tr.tile[w4 + j][c] = (bf16_t)v[j];
  }
  // reduce sums over the 16 w-groups (lanes sharing cr form 16-lane runs)
#pragma unroll
  for (int k = 0; k < 8; ++k) {
    float s = csum[k];
    s += __shfl_down(s, 8, 16);
    s += __shfl_down(s, 4, 16);
    s += __shfl_down(s, 2, 16);
    s += __shfl_down(s, 1, 16);
    if (wg == 0) sm.tr.cred[cr + k * 16] = s;   // exclusive slots, plain store
  }
  __syncthreads();
  if (tid < 128) atomicAdd(&ctxs[tb * 128 + tid], sm.tr.cred[tid]);
  // store: bf16x8 rows (pure LDS b128 read -> coalesced 16B global store)
  bf16_t* dst = ftr + ((size_t)tb * HW + hw0) * 128;
  int cb = wg * 8;
#pragma unroll
  for (int i = 0; i < 4; ++i) {
    int p = cr + 16 * i;
    bf16x8 v = *(const bf16x8*)&sm.tr.tile[p][cb];
    *(bf16x8*)(dst + (size_t)p * 128 + cb) = v;
  }
}

// ---------------------------------------------------------------------------
// Kernel B: main — one block per match n. Gather -> MFMA -> LDS-staged
// coalesced nontemporal output (+precomputed g, bias folded into g).
// ---------------------------------------------------------------------------
__global__ __launch_bounds__(256, 6) void main_kernel(
    const bf16_t* __restrict__ ftr,
    const int* __restrict__ b_ids, const int* __restrict__ i_ids,
    const int* __restrict__ j_ids, const int* __restrict__ w0c_p,
    const int* __restrict__ w1c_p, const float* __restrict__ ctxs,
    const bf16_t* __restrict__ A_swz, const float* __restrict__ g,
    float* __restrict__ out) {
  __shared__ __align__(16) union {
    bf16_t sV[3][32][PAD];     // 0: p0*p1, 1: p0*cs1, 2: p1*cs0  (26112 B)
    float  so[2][25 * 128];    // f32 output staging, aliased after MFMA
  } sm;

  int n = blockIdx.x;
  int tid = threadIdx.x;
  int b = b_ids[n], ii = i_ids[n], jj = j_ids[n];
  int w0c = w0c_p[0], w1c = w1c_p[0];
  int x0 = min((ii % w0c) * 2, WF - 1), y0 = min((ii / w0c) * 2, HF - 1);
  int x1 = min((jj % w1c) * 2, WF - 1), y1 = min((jj / w1c) * 2, HF - 1);

  // ---- gather: 8 lanes per patch position (rows 25..31 left stale: their
  //      MFMA output rows are discarded by the row<25 guard) ----
  int grp = tid >> 3, e = tid & 7;
  if (grp < 25) {
    const bf16_t* base0 = ftr + (size_t)b * HW * 128;
    const bf16_t* base1 = ftr + (size_t)(2 + b) * HW * 128;
    int dy = grp / 5 - 2, dx = grp % 5 - 2;
    int ya = y0 + dy, xa = x0 + dx;
    int yb = y1 + dy, xb = x1 + dx;
    bool v0 = (ya >= 0 && ya < HF && xa >= 0 && xa < WF);
    bool v1 = (yb >= 0 && yb < HF && xb >= 0 && xb < WF);
    const bf16_t* r0 = base0 + ((size_t)(v0 ? ya * WF + xa : 0)) * 128;
    const bf16_t* r1 = base1 + ((size_t)(v1 ? yb * WF + xb : 0)) * 128;
    const float ksc = INV_S / (float)HW;   // ctxs holds raw sums
#pragma unroll
    for (int h = 0; h < 2; ++h) {
      int cb = h * 64 + e * 8;
      bf16x8 a0 = *(const bf16x8*)(r0 + cb);
      bf16x8 a1 = *(const bf16x8*)(r1 + cb);
      f32x4 cs0a = *(const f32x4*)&ctxs[b * 128 + cb];
      f32x4 cs0b = *(const f32x4*)&ctxs[b * 128 + cb + 4];
      f32x4 cs1a = *(const f32x4*)&ctxs[256 + b * 128 + cb];
      f32x4 cs1b = *(const f32x4*)&ctxs[256 + b * 128 + cb + 4];
      bf16x8 oP, o1, o2;
#pragma unroll
      for (int j = 0; j < 8; ++j) {
        float p0 = v0 ? (float)a0[j] : 0.f;
        float p1 = v1 ? (float)a1[j] : 0.f;
        float c0f = (j < 4 ? cs0a[j & 3] : cs0b[j & 3]) * ksc;
        float c1f = (j < 4 ? cs1a[j & 3] : cs1b[j & 3]) * ksc;
        oP[j] = (bf16_t)(p0 * p1);
        o1[j] = (bf16_t)(p0 * c1f);
        o2[j] = (bf16_t)(p1 * c0f);
      }
      *(bf16x8*)&sm.sV[0][grp][cb] = oP;
      *(bf16x8*)&sm.sV[1][grp][cb] = o1;
      *(bf16x8*)&sm.sV[2][grp][cb] = o2;
    }
  }
  __syncthreads();

  // ---- MFMA phase ----
  int w = tid >> 6, lane = tid & 63, quad = lane >> 4, lr = lane & 15;
  f32x4 accP[2][2] = {};   // vp@A0 (shared by both outputs)
  f32x4 acc01[2][2] = {};  // v0@A1 + v1@A2  (-> out0)
  f32x4 acc10[2][2] = {};  // v1@A1 + v0@A2  (-> out1)

#pragma unroll
  for (int ks = 0; ks < 4; ++ks) {
    bf16x8 va[2][3];
#pragma unroll
    for (int mt = 0; mt < 2; ++mt)
#pragma unroll
      for (int m = 0; m < 3; ++m)
        va[mt][m] = *(const bf16x8*)&sm.sV[m][mt * 16 + lr][ks * 32 + quad * 8];
    bf16x8 vb[3][2];
#pragma unroll
    for (int m = 0; m < 3; ++m)
#pragma unroll
      for (int ntl = 0; ntl < 2; ++ntl) {
        int nt = w * 2 + ntl;
        vb[m][ntl] = *(const bf16x8*)(A_swz + m * 16384 + (((nt * 4 + ks) * 64) + lane) * 8);
      }
#pragma unroll
    for (int mt = 0; mt < 2; ++mt)
#pragma unroll
      for (int ntl = 0; ntl < 2; ++ntl) {
        accP[mt][ntl]  = __builtin_amdgcn_mfma_f32_16x16x32_bf16(va[mt][0], vb[0][ntl], accP[mt][ntl], 0, 0, 0);
        acc01[mt][ntl] = __builtin_amdgcn_mfma_f32_16x16x32_bf16(va[mt][1], vb[1][ntl], acc01[mt][ntl], 0, 0, 0);
        acc01[mt][ntl] = __builtin_amdgcn_mfma_f32_16x16x32_bf16(va[mt][2], vb[2][ntl], acc01[mt][ntl], 0, 0, 0);
        acc10[mt][ntl] = __builtin_amdgcn_mfma_f32_16x16x32_bf16(va[mt][2], vb[1][ntl], acc10[mt][ntl], 0, 0, 0);
        acc10[mt][ntl] = __builtin_amdgcn_mfma_f32_16x16x32_bf16(va[mt][1], vb[2][ntl], acc10[mt][ntl], 0, 0, 0);
      }
  }
  __syncthreads();   // everyone done reading sV before aliasing as so

  // ---- stage C tiles to LDS (C/D: col=lane&15(+tiles), row=quad*4+reg) ----
#pragma unroll
  for (int ntl = 0; ntl < 2; ++ntl) {
    int col = w * 32 + ntl * 16 + lr;
#pragma unroll
    for (int mt = 0; mt < 2; ++mt)
#pragma unroll
      for (int rg = 0; rg < 4; ++rg) {
        int row = mt * 16 + quad * 4 + rg;
        if (row < 25) {
          sm.so[0][row * 128 + col] = accP[mt][ntl][rg] + acc01[mt][ntl][rg];
          sm.so[1][row * 128 + col] = accP[mt][ntl][rg] + acc10[mt][ntl][rg];
        }
      }
  }
  __syncthreads();

  // ---- coalesced nontemporal write-out, adding g (bias already folded) ----
  float* o0 = out + (size_t)n * 3200;
  float* o1 = out + (size_t)NPTS * 3200 + (size_t)n * 3200;
  const float* g0 = g + (size_t)n * 128;
  const float* g1 = g + (size_t)(NPTS + n) * 128;
  for (int i = tid; i < 800; i += 256) {
    int f = i * 4, c = f & 127;
    f32x4 gv0 = *(const f32x4*)(g0 + c);
    f32x4 gv1 = *(const f32x4*)(g1 + c);
    f32x4 v0 = *(const f32x4*)&sm.so[0][f];
    f32x4 v1 = *(const f32x4*)&sm.so[1][f];
    __builtin_nontemporal_store(v0 + gv0, (f32x4*)(o0 + f));
    __builtin_nontemporal_store(v1 + gv1, (f32x4*)(o1 + f));
  }
}

// ---------------------------------------------------------------------------
// Fallback (ws too small for ftr+g): direct f32 gather + fused fc dot.
// ---------------------------------------------------------------------------
__global__ __launch_bounds__(256) void ctx_mean_f32_kernel(
    const float* __restrict__ f0, const float* __restrict__ f1,
    float* __restrict__ ctxs) {
  int id = blockIdx.x;
  const float* src = (id < 256 ? f0 : f1) + (size_t)(id & 255) * HW;
  float s = 0.f;
  for (int i = threadIdx.x; i < HW; i += 256) s += src[i];
  for (int off = 32; off > 0; off >>= 1) s += __shfl_down(s, off, 64);
  __shared__ float part[4];
  if ((threadIdx.x & 63) == 0) part[threadIdx.x >> 6] = s;
  __syncthreads();
  if (threadIdx.x == 0) ctxs[id] = part[0] + part[1] + part[2] + part[3];
}

__global__ __launch_bounds__(256, 4) void main_fallback_kernel(
    const float* __restrict__ f0, const float* __restrict__ f1,
    const float* __restrict__ fc0, const float* __restrict__ fc1,
    const int* __restrict__ b_ids, const int* __restrict__ i_ids,
    const int* __restrict__ j_ids, const int* __restrict__ w0c_p,
    const int* __restrict__ w1c_p, const float* __restrict__ ctxs,
    const float* __restrict__ bias_all, const bf16_t* __restrict__ A_swz,
    const bf16_t* __restrict__ DmB, float* __restrict__ out) {
  __shared__ __align__(16) bf16_t sV[3][32][PAD];
  __shared__ float sg[2][128];
  int n = blockIdx.x;
  int tid = threadIdx.x;
  int b = b_ids[n], ii = i_ids[n], jj = j_ids[n];
  int w0c = w0c_p[0], w1c = w1c_p[0];
  int x0 = min((ii % w0c) * 2, WF - 1), y0 = min((ii / w0c) * 2, HF - 1);
  int x1 = min((jj % w1c) * 2, WF - 1), y1 = min((jj / w1c) * 2, HF - 1);
  const float ksc = INV_S / (float)HW;
  int c = tid & 127, kh = tid >> 7;
  float cs0 = ctxs[b * 128 + c] * ksc;
  float cs1 = ctxs[256 + b * 128 + c] * ksc;
  const float* f0b = f0 + (size_t)(b * 128 + c) * HW;
  const float* f1b = f1 + (size_t)(b * 128 + c) * HW;
  for (int k = kh; k < 32; k += 2) {
    float p0 = 0.f, p1 = 0.f;
    if (k < 25) {
      int dy = k / 5 - 2, dx = k % 5 - 2;
      int ya = y0 + dy, xa = x0 + dx;
      if (ya >= 0 && ya < HF && xa >= 0 && xa < WF) p0 = f0b[ya * WF + xa];
      int yb = y1 + dy, xb = x1 + dx;
      if (yb >= 0 && yb < HF && xb >= 0 && xb < WF) p1 = f1b[yb * WF + xb];
    }
    sV[0][k][c] = (bf16_t)(p0 * p1);
    sV[1][k][c] = (bf16_t)(p0 * cs1);
    sV[2][k][c] = (bf16_t)(p1 * cs0);
  }
  {
    int h = tid >> 7, col = tid & 127;
    const float* fcrow = h ? fc1 + ((size_t)b * LC + jj) * D_C
                           : fc0 + ((size_t)b * LC + ii) * D_C;
    const bf16_t* dbase = DmB + col * 8;
    float p0 = 0.f, p1 = 0.f, p2 = 0.f, p3 = 0.f;
#pragma unroll 4
    for (int t8 = 0; t8 < 32; ++t8) {
      bf16x8 d  = *(const bf16x8*)(dbase + t8 * 1024);
      f32x4  fa = *(const f32x4*)(fcrow + t8 * 8);
      f32x4  fb = *(const f32x4*)(fcrow + t8 * 8 + 4);
      p0 += fa[0] * (float)d[0] + fb[0] * (float)d[4];
      p1 += fa[1] * (float)d[1] + fb[1] * (float)d[5];
      p2 += fa[2] * (float)d[2] + fb[2] * (float)d[6];
      p3 += fa[3] * (float)d[3] + fb[3] * (float)d[7];
    }
    sg[h][col] = ((p0 + p1) + (p2 + p3));
  }
  __syncthreads();
  int w = tid >> 6, lane = tid & 63, quad = lane >> 4, lr = lane & 15;
  f32x4 accP[2][2] = {}, acc01[2][2] = {}, acc10[2][2] = {};
#pragma unroll
  for (int ks = 0; ks < 4; ++ks) {
    bf16x8 va[2][3];
#pragma unroll
    for (int mt = 0; mt < 2; ++mt)
#pragma unroll
      for (int m = 0; m < 3; ++m)
        va[mt][m] = *(const bf16x8*)&sV[m][mt * 16 + lr][ks * 32 + quad * 8];
    bf16x8 vb[3][2];
#pragma unroll
    for (int m = 0; m < 3; ++m)
#pragma unroll
      for (int ntl = 0; ntl < 2; ++ntl) {
        int nt = w * 2 + ntl;
        vb[m][ntl] = *(const bf16x8*)(A_swz + m * 16384 + (((nt * 4 + ks) * 64) + lane) * 8);
      }
#pragma unroll
    for (int mt = 0; mt < 2; ++mt)
#pragma unroll
      for (int ntl = 0; ntl < 2; ++ntl) {
        accP[mt][ntl]  = __builtin_amdgcn_mfma_f32_16x16x32_bf16(va[mt][0], vb[0][ntl], accP[mt][ntl], 0, 0, 0);
        acc01[mt][ntl] = __builtin_amdgcn_mfma_f32_16x16x32_bf16(va[mt][1], vb[1][ntl], acc01[mt][ntl], 0, 0, 0);
        acc01[mt][ntl] = __builtin_amdgcn_mfma_f32_16x16x32_bf16(va[mt][2], vb[2][ntl], acc01[mt][ntl], 0, 0, 0);
        acc10[mt][ntl] = __builtin_amdgcn_mfma_f32_16x16x32_bf16(va[mt][2], vb[1][ntl], acc10[mt][ntl], 0, 0, 0);
        acc10[mt][ntl] = __builtin_amdgcn_mfma_f32_16x16x32_bf16(va[mt][1], vb[2][ntl], acc10[mt][ntl], 0, 0, 0);
      }
  }
#pragma unroll
  for (int ntl = 0; ntl < 2; ++ntl) {
    int col = w * 32 + ntl * 16 + lr;
    float bg = bias_all[col];
    float gg0 = sg[0][col] + bg, gg1 = sg[1][col] + bg;
#pragma unroll
    for (int mt = 0; mt < 2; ++mt)
#pragma unroll
      for (int rg = 0; rg < 4; ++rg) {
        int row = mt * 16 + quad * 4 + rg;
        if (row < 25) {
          size_t o = ((size_t)n * 25 + row) * 128 + col;
          out[o] = accP[mt][ntl][rg] + acc01[mt][ntl][rg] + gg0;
          out[(size_t)NPTS * 25 * 128 + o] = accP[mt][ntl][rg] + acc10[mt][ntl][rg] + gg1;
        }
      }
  }
}

// ---------------------------------------------------------------------------
extern "C" void kernel_launch(void* const* d_in, const int* in_sizes, int n_in,
                              void* d_out, int out_size, void* d_ws, size_t ws_size,
                              hipStream_t stream) {
  const float* f0     = (const float*)d_in[0];
  const float* f1     = (const float*)d_in[1];
  const float* fc0    = (const float*)d_in[2];
  const float* fc1    = (const float*)d_in[3];
  const float* corr_w = (const float*)d_in[4];
  const float* corr_b = (const float*)d_in[5];
  const float* dp_w   = (const float*)d_in[6];
  const float* dp_b   = (const float*)d_in[7];
  const float* mg_w   = (const float*)d_in[8];
  const float* mg_b   = (const float*)d_in[9];
  const int* b_ids    = (const int*)d_in[10];
  const int* i_ids    = (const int*)d_in[11];
  const int* j_ids    = (const int*)d_in[12];
  const int* w0c      = (const int*)d_in[13];
  const int* w1c      = (const int*)d_in[14];

  char* ws = (char*)d_ws;
  float*  ctxs     = (float*)(ws);
  float*  bias_all = (float*)(ws + 4096);
  bf16_t* A_swz    = (bf16_t*)(ws + 8192);
  bf16_t* DmB      = (bf16_t*)(ws + 106496);
  bf16_t* ftr      = (bf16_t*)(ws + FTR_OFF);
  float*  g        = (float*)(ws + G_OFF);
  int fast = (ws_size >= G_OFF + G_BYTES) ? 1 : 0;

  if (fast) {
    hipMemsetAsync(ctxs, 0, 2048, stream);
    // g (625) + prep (641) + transpose (2704) fused: one dispatch, all
    // three parts independent (g uses original weights, not prep output).
    ptg_kernel<<<PTG_GRID, 256, 0, stream>>>(
        f0, f1, fc0, fc1, corr_w, corr_b, dp_w, dp_b, mg_w, mg_b,
        b_ids, i_ids, j_ids, A_swz, DmB, bias_all, ftr, ctxs, g);
    main_kernel<<<NPTS, 256, 0, stream>>>(ftr, b_ids, i_ids, j_ids, w0c, w1c,
                                          ctxs, A_swz, g, (float*)d_out);
  } else {
    // prep-only dispatch (grid==641 -> every block runs the prep role)
    ptg_kernel<<<641, 256, 0, stream>>>(
        f0, f1, fc0, fc1, corr_w, corr_b, dp_w, dp_b, mg_w, mg_b,
        b_ids, i_ids, j_ids, A_swz, DmB, bias_all, ftr, ctxs, g);
    ctx_mean_f32_kernel<<<512, 256, 0, stream>>>(f0, f1, ctxs);
    main_fallback_kernel<<<NPTS, 256, 0, stream>>>(f0, f1, fc0, fc1, b_ids,
                                                   i_ids, j_ids, w0c, w1c, ctxs,
                                                   bias_all, A_swz, DmB,
                                                   (float*)d_out);
  }
}

// Round 8
// 322.587 us; speedup vs baseline: 2.3344x; 1.0230x over previous
//
#include <hip/hip_runtime.h>

#define HF   208
#define WF   208
#define D_C  256
#define LC   10816
#define NPTS 5000
#define HW   (HF*WF)                    // 43264
#define INV_S 0.08838834764831845f      // 1/sqrt(128)
#define PAD  136                        // bf16 row pad for sV

// ptg block-role partition (fast path): [g][prep][transpose]
#define G_BLOCKS    625                 // 16 rows each -> 10000 rows
#define PREP_BLOCKS 641
#define TR_BLOCKS   2704                // 4 tb * 676 tiles of 64 rows
#define PTG_GRID    (G_BLOCKS + PREP_BLOCKS + TR_BLOCKS)   // 3970

typedef __bf16 bf16_t;
typedef __bf16 bf16x8 __attribute__((ext_vector_type(8)));
typedef float  f32x4  __attribute__((ext_vector_type(4)));

// Workspace layout:
//   +0        float ctxs[512]       raw channel sums (atomic), scaled in main
//   +4096     float bias_all[128]   mg_b + corr_b@mg_w1 + dp_b@mg_w2
//   +8192     bf16  A_swz[3*16384]  B-fragment-swizzled fused mats
//   +106496   bf16  DmB[32][128][8] down_proj@merge fused, t-blocked (fallback)
//   +172032   bf16  ftr[2][2][HW][128]   44.30 MB transposed features
//   +FTR_END  float g[10000][128]        5.12 MB  (fc@dp_w)@mg_w2 RAW (no bias)
#define FTR_OFF   172032
#define FTR_BYTES ((size_t)2*2*HW*128*2)
#define G_OFF     (FTR_OFF + FTR_BYTES)
#define G_BYTES   ((size_t)2*NPTS*128*4)

// ---------------------------------------------------------------------------
// Kernel A (fused, one dispatch; role order = [g][prep][transpose]).
//   g:        16 rows/block, g_raw[r] = (fc_r@dp_w)@mg_w2  (NO bias terms --
//             bias_all is added by main; removes the per-block serial
//             corr_b@mg_w1 loop). Contiguous f32x4 weight loads.
//   prep:     fused-weight precompute (A_swz, DmB, bias_all)
//   transpose:(B,C,H,W) f32 -> (t,b,HW,C) bf16 + channel sums. bf16 LDS
//             tile with chunk-XOR swizzle (writes ~2-way instead of 16-way
//             bank conflict); 8 hoisted loads for MLP.
// __launch_bounds__(256,8): VGPR cap 64. Fallback dispatch grid=641 -> prep.
// ---------------------------------------------------------------------------
__global__ __launch_bounds__(256, 8) void ptg_kernel(
    const float* __restrict__ f0, const float* __restrict__ f1,
    const float* __restrict__ fc0, const float* __restrict__ fc1,
    const float* __restrict__ corr_w, const float* __restrict__ corr_b,
    const float* __restrict__ dp_w,   const float* __restrict__ dp_b,
    const float* __restrict__ mg_w,   const float* __restrict__ mg_b,
    const int* __restrict__ b_ids, const int* __restrict__ i_ids,
    const int* __restrict__ j_ids,
    bf16_t* __restrict__ A_swz, bf16_t* __restrict__ DmB,
    float* __restrict__ bias_all,
    bf16_t* __restrict__ ftr, float* __restrict__ ctxs,
    float* __restrict__ g) {
  __shared__ __align__(16) union {
    struct { bf16_t tile[64][136]; float cred[128]; } tr;  // 17920 B
    float s_src[16][256];                                  // 16384 B (g part)
  } sm;
  int bid = blockIdx.x;
  int tid = threadIdx.x;

  int prep_id = -1;
  if (gridDim.x == 641) {
    prep_id = bid;                       // fallback: prep-only dispatch
  } else if (bid >= G_BLOCKS && bid < G_BLOCKS + PREP_BLOCKS) {
    prep_id = bid - G_BLOCKS;
  }

  if (prep_id >= 0) {                  // ---- prep part (128 active threads)
    if (tid >= 128) return;
    int c = tid;
    if (prep_id < 384) {
      int mat = prep_id >> 7, r = prep_id & 127;
      float acc = 0.f;
      for (int t = 0; t < 128; ++t)
        acc += corr_w[(mat * 128 + r) * 128 + t] * mg_w[t * 128 + c];
      if (mat == 0) acc *= INV_S;
      // B-fragment swizzle (mfma_f32_16x16x32_bf16): (k=r,n=c) ->
      // lane=((k&31)>>3)*16+(n&15), j=k&7, tiles (nt=n>>4, ks=k>>5)
      int ks = r >> 5, quad = (r & 31) >> 3, jj = r & 7;
      int nt = c >> 4, lr = c & 15;
      A_swz[mat * 16384 + (((nt * 4 + ks) * 64) + quad * 16 + lr) * 8 + jj] = (bf16_t)acc;
    } else if (prep_id < 640) {
      int r = prep_id - 384;
      float acc = 0.f;
      for (int t = 0; t < 128; ++t)
        acc += dp_w[r * 128 + t] * mg_w[(128 + t) * 128 + c];
      DmB[(((r >> 3) * 128) + c) * 8 + (r & 7)] = (bf16_t)acc;   // fallback only
    } else {
      float acc = mg_b[c];
      for (int t = 0; t < 128; ++t) {
        acc += corr_b[t] * mg_w[t * 128 + c];
        acc += dp_b[t]   * mg_w[(128 + t) * 128 + c];
      }
      bias_all[c] = acc;               // added by main (fast) / fallback
    }
    return;
  }

  if (bid < G_BLOCKS) {                // ---- g part: g_raw = (fc@dp_w)@mg_w2
    int r0 = bid * 16;
    // stage 16 fc rows, f32x4 coalesced, one wave per 4 rows
    {
      int l = tid & 63, wv = tid >> 6;
      for (int k2 = 0; k2 < 4; ++k2) {
        int rr = wv * 4 + k2;
        int r = r0 + rr;
        const float* src;
        int b, idx;
        if (r < NPTS) { b = b_ids[r]; idx = i_ids[r]; src = fc0; }
        else          { b = b_ids[r - NPTS]; idx = j_ids[r - NPTS]; src = fc1; }
        f32x4 val = *(const f32x4*)&src[((size_t)b * LC + idx) * D_C + l * 4];
        *(f32x4*)&sm.s_src[rr][l * 4] = val;
      }
    }
    __syncthreads();
    int cg = tid & 31, rg = tid >> 5;  // cols cg*4..+3, rows rg*2, rg*2+1
    const f32x4* dpw4 = (const f32x4*)dp_w;          // [256][32] f32x4
    f32x4 h0 = {0.f, 0.f, 0.f, 0.f}, h1 = {0.f, 0.f, 0.f, 0.f};
    for (int t = 0; t < 256; t += 4) {
      f32x4 w0 = dpw4[(t + 0) * 32 + cg];
      f32x4 w1 = dpw4[(t + 1) * 32 + cg];
      f32x4 w2 = dpw4[(t + 2) * 32 + cg];
      f32x4 w3 = dpw4[(t + 3) * 32 + cg];
      f32x4 s0 = *(const f32x4*)&sm.s_src[rg * 2][t];
      f32x4 s1 = *(const f32x4*)&sm.s_src[rg * 2 + 1][t];
      h0 += w0 * s0[0] + w1 * s0[1] + w2 * s0[2] + w3 * s0[3];
      h1 += w0 * s1[0] + w1 * s1[1] + w2 * s1[2] + w3 * s1[3];
    }
    __syncthreads();
    float* s_h = &sm.s_src[0][0];      // reuse as [16][128]
    *(f32x4*)&s_h[(rg * 2) * 128 + cg * 4]     = h0;
    *(f32x4*)&s_h[(rg * 2 + 1) * 128 + cg * 4] = h1;
    __syncthreads();
    const f32x4* mgw4 = (const f32x4*)(mg_w + 128 * 128);   // [128][32] f32x4
    f32x4 a0 = {0.f, 0.f, 0.f, 0.f}, a1 = {0.f, 0.f, 0.f, 0.f};
    for (int t = 0; t < 128; t += 4) {
      f32x4 w0 = mgw4[(t + 0) * 32 + cg];
      f32x4 w1 = mgw4[(t + 1) * 32 + cg];
      f32x4 w2 = mgw4[(t + 2) * 32 + cg];
      f32x4 w3 = mgw4[(t + 3) * 32 + cg];
      f32x4 s0 = *(const f32x4*)&s_h[(rg * 2) * 128 + t];
      f32x4 s1 = *(const f32x4*)&s_h[(rg * 2 + 1) * 128 + t];
      a0 += w0 * s0[0] + w1 * s0[1] + w2 * s0[2] + w3 * s0[3];
      a1 += w0 * s1[0] + w1 * s1[1] + w2 * s1[2] + w3 * s1[3];
    }
    *(f32x4*)&g[(size_t)(r0 + rg * 2) * 128 + cg * 4]     = a0;
    *(f32x4*)&g[(size_t)(r0 + rg * 2 + 1) * 128 + cg * 4] = a1;
    return;
  }

  // ---- transpose part: 64-row tiles, bf16 LDS, chunk-XOR swizzle ----
  int tbid = bid - (G_BLOCKS + PREP_BLOCKS);   // 0..2703
  int tb = tbid / 676;                         // t*2+b
  int hw0 = (tbid % 676) * 64;
  const float* src = (tb < 2 ? f0 : f1) + (size_t)((tb & 1) * 128) * HW;
  int wg = tid & 15, cr = tid >> 4;            // wg: w-group, cr: 0..15
  int w4 = wg * 4;
  // hoisted loads: all 8 in flight before LDS writes (MLP)
  f32x4 v[8];
#pragma unroll
  for (int k = 0; k < 8; ++k) {
    int c = cr + k * 16;
    v[k] = *(const f32x4*)&src[(size_t)c * HW + hw0 + w4];
  }
  // swizzled LDS writes + channel sums (from f32, exact)
  float csum[8];
  int wmask = wg & 7;                          // (row>>2)&7 with row=w4+j, j<4
#pragma unroll
  for (int k = 0; k < 8; ++k) {
    int c = cr + k * 16;
    csum[k] = (v[k][0] + v[k][1]) + (v[k][2] + v[k][3]);
    int cs = (((c >> 3) ^ wmask) << 3) | (c & 7);
#pragma unroll
    for (int j = 0; j < 4; ++j) sm.tr.tile[w4 + j][cs] = (bf16_t)v[k][j];
  }
  // reduce sums over the 16 w-groups (lanes sharing cr form 16-lane runs)
#pragma unroll
  for (int k = 0; k < 8; ++k) {
    float s = csum[k];
    s += __shfl_down(s, 8, 16);
    s += __shfl_down(s, 4, 16);
    s += __shfl_down(s, 2, 16);
    s += __shfl_down(s, 1, 16);
    if (wg == 0) sm.tr.cred[cr + k * 16] = s;   // exclusive slots, plain store
  }
  __syncthreads();
  if (tid < 128) atomicAdd(&ctxs[tb * 128 + tid], sm.tr.cred[tid]);
  // store: bf16x8 rows, read with matching swizzle
  bf16_t* dst = ftr + ((size_t)tb * HW + hw0) * 128;
#pragma unroll
  for (int i = 0; i < 4; ++i) {
    int p = cr + 16 * i;
    int cs = (wg ^ ((p >> 2) & 7)) << 3;
    bf16x8 vv = *(const bf16x8*)&sm.tr.tile[p][cs];
    *(bf16x8*)(dst + (size_t)p * 128 + wg * 8) = vv;
  }
}

// ---------------------------------------------------------------------------
// Kernel B: main — one block per match n. Gather -> MFMA -> LDS-staged
// coalesced nontemporal output (+g_raw +bias_all).
// ---------------------------------------------------------------------------
__global__ __launch_bounds__(256, 6) void main_kernel(
    const bf16_t* __restrict__ ftr,
    const int* __restrict__ b_ids, const int* __restrict__ i_ids,
    const int* __restrict__ j_ids, const int* __restrict__ w0c_p,
    const int* __restrict__ w1c_p, const float* __restrict__ ctxs,
    const bf16_t* __restrict__ A_swz, const float* __restrict__ g,
    const float* __restrict__ bias_all, float* __restrict__ out) {
  __shared__ __align__(16) union {
    bf16_t sV[3][32][PAD];     // 0: p0*p1, 1: p0*cs1, 2: p1*cs0  (26112 B)
    float  so[2][25 * 128];    // f32 output staging, aliased after MFMA
  } sm;

  int n = blockIdx.x;
  int tid = threadIdx.x;
  int b = b_ids[n], ii = i_ids[n], jj = j_ids[n];
  int w0c = w0c_p[0], w1c = w1c_p[0];
  int x0 = min((ii % w0c) * 2, WF - 1), y0 = min((ii / w0c) * 2, HF - 1);
  int x1 = min((jj % w1c) * 2, WF - 1), y1 = min((jj / w1c) * 2, HF - 1);

  // ---- gather: 8 lanes per patch position (rows 25..31 left stale: their
  //      MFMA output rows are discarded by the row<25 guard) ----
  int grp = tid >> 3, e = tid & 7;
  if (grp < 25) {
    const bf16_t* base0 = ftr + (size_t)b * HW * 128;
    const bf16_t* base1 = ftr + (size_t)(2 + b) * HW * 128;
    int dy = grp / 5 - 2, dx = grp % 5 - 2;
    int ya = y0 + dy, xa = x0 + dx;
    int yb = y1 + dy, xb = x1 + dx;
    bool v0 = (ya >= 0 && ya < HF && xa >= 0 && xa < WF);
    bool v1 = (yb >= 0 && yb < HF && xb >= 0 && xb < WF);
    const bf16_t* r0 = base0 + ((size_t)(v0 ? ya * WF + xa : 0)) * 128;
    const bf16_t* r1 = base1 + ((size_t)(v1 ? yb * WF + xb : 0)) * 128;
    const float ksc = INV_S / (float)HW;   // ctxs holds raw sums
#pragma unroll
    for (int h = 0; h < 2; ++h) {
      int cb = h * 64 + e * 8;
      bf16x8 a0 = *(const bf16x8*)(r0 + cb);
      bf16x8 a1 = *(const bf16x8*)(r1 + cb);
      f32x4 cs0a = *(const f32x4*)&ctxs[b * 128 + cb];
      f32x4 cs0b = *(const f32x4*)&ctxs[b * 128 + cb + 4];
      f32x4 cs1a = *(const f32x4*)&ctxs[256 + b * 128 + cb];
      f32x4 cs1b = *(const f32x4*)&ctxs[256 + b * 128 + cb + 4];
      bf16x8 oP, o1, o2;
#pragma unroll
      for (int j = 0; j < 8; ++j) {
        float p0 = v0 ? (float)a0[j] : 0.f;
        float p1 = v1 ? (float)a1[j] : 0.f;
        float c0f = (j < 4 ? cs0a[j & 3] : cs0b[j & 3]) * ksc;
        float c1f = (j < 4 ? cs1a[j & 3] : cs1b[j & 3]) * ksc;
        oP[j] = (bf16_t)(p0 * p1);
        o1[j] = (bf16_t)(p0 * c1f);
        o2[j] = (bf16_t)(p1 * c0f);
      }
      *(bf16x8*)&sm.sV[0][grp][cb] = oP;
      *(bf16x8*)&sm.sV[1][grp][cb] = o1;
      *(bf16x8*)&sm.sV[2][grp][cb] = o2;
    }
  }
  __syncthreads();

  // ---- MFMA phase ----
  int w = tid >> 6, lane = tid & 63, quad = lane >> 4, lr = lane & 15;
  f32x4 accP[2][2] = {};   // vp@A0 (shared by both outputs)
  f32x4 acc01[2][2] = {};  // v0@A1 + v1@A2  (-> out0)
  f32x4 acc10[2][2] = {};  // v1@A1 + v0@A2  (-> out1)

#pragma unroll
  for (int ks = 0; ks < 4; ++ks) {
    bf16x8 va[2][3];
#pragma unroll
    for (int mt = 0; mt < 2; ++mt)
#pragma unroll
      for (int m = 0; m < 3; ++m)
        va[mt][m] = *(const bf16x8*)&sm.sV[m][mt * 16 + lr][ks * 32 + quad * 8];
    bf16x8 vb[3][2];
#pragma unroll
    for (int m = 0; m < 3; ++m)
#pragma unroll
      for (int ntl = 0; ntl < 2; ++ntl) {
        int nt = w * 2 + ntl;
        vb[m][ntl] = *(const bf16x8*)(A_swz + m * 16384 + (((nt * 4 + ks) * 64) + lane) * 8);
      }
#pragma unroll
    for (int mt = 0; mt < 2; ++mt)
#pragma unroll
      for (int ntl = 0; ntl < 2; ++ntl) {
        accP[mt][ntl]  = __builtin_amdgcn_mfma_f32_16x16x32_bf16(va[mt][0], vb[0][ntl], accP[mt][ntl], 0, 0, 0);
        acc01[mt][ntl] = __builtin_amdgcn_mfma_f32_16x16x32_bf16(va[mt][1], vb[1][ntl], acc01[mt][ntl], 0, 0, 0);
        acc01[mt][ntl] = __builtin_amdgcn_mfma_f32_16x16x32_bf16(va[mt][2], vb[2][ntl], acc01[mt][ntl], 0, 0, 0);
        acc10[mt][ntl] = __builtin_amdgcn_mfma_f32_16x16x32_bf16(va[mt][2], vb[1][ntl], acc10[mt][ntl], 0, 0, 0);
        acc10[mt][ntl] = __builtin_amdgcn_mfma_f32_16x16x32_bf16(va[mt][1], vb[2][ntl], acc10[mt][ntl], 0, 0, 0);
      }
  }
  __syncthreads();   // everyone done reading sV before aliasing as so

  // ---- stage C tiles to LDS (C/D: col=lane&15(+tiles), row=quad*4+reg) ----
#pragma unroll
  for (int ntl = 0; ntl < 2; ++ntl) {
    int col = w * 32 + ntl * 16 + lr;
#pragma unroll
    for (int mt = 0; mt < 2; ++mt)
#pragma unroll
      for (int rg = 0; rg < 4; ++rg) {
        int row = mt * 16 + quad * 4 + rg;
        if (row < 25) {
          sm.so[0][row * 128 + col] = accP[mt][ntl][rg] + acc01[mt][ntl][rg];
          sm.so[1][row * 128 + col] = accP[mt][ntl][rg] + acc10[mt][ntl][rg];
        }
      }
  }
  __syncthreads();

  // ---- coalesced nontemporal write-out, adding g_raw + bias_all ----
  float* o0 = out + (size_t)n * 3200;
  float* o1 = out + (size_t)NPTS * 3200 + (size_t)n * 3200;
  const float* g0 = g + (size_t)n * 128;
  const float* g1 = g + (size_t)(NPTS + n) * 128;
  for (int i = tid; i < 800; i += 256) {
    int f = i * 4, c = f & 127;
    f32x4 bv  = *(const f32x4*)(bias_all + c);
    f32x4 gv0 = *(const f32x4*)(g0 + c) + bv;
    f32x4 gv1 = *(const f32x4*)(g1 + c) + bv;
    f32x4 v0 = *(const f32x4*)&sm.so[0][f];
    f32x4 v1 = *(const f32x4*)&sm.so[1][f];
    __builtin_nontemporal_store(v0 + gv0, (f32x4*)(o0 + f));
    __builtin_nontemporal_store(v1 + gv1, (f32x4*)(o1 + f));
  }
}

// ---------------------------------------------------------------------------
// Fallback (ws too small for ftr+g): direct f32 gather + fused fc dot.
// ---------------------------------------------------------------------------
__global__ __launch_bounds__(256) void ctx_mean_f32_kernel(
    const float* __restrict__ f0, const float* __restrict__ f1,
    float* __restrict__ ctxs) {
  int id = blockIdx.x;
  const float* src = (id < 256 ? f0 : f1) + (size_t)(id & 255) * HW;
  float s = 0.f;
  for (int i = threadIdx.x; i < HW; i += 256) s += src[i];
  for (int off = 32; off > 0; off >>= 1) s += __shfl_down(s, off, 64);
  __shared__ float part[4];
  if ((threadIdx.x & 63) == 0) part[threadIdx.x >> 6] = s;
  __syncthreads();
  if (threadIdx.x == 0) ctxs[id] = part[0] + part[1] + part[2] + part[3];
}

__global__ __launch_bounds__(256, 4) void main_fallback_kernel(
    const float* __restrict__ f0, const float* __restrict__ f1,
    const float* __restrict__ fc0, const float* __restrict__ fc1,
    const int* __restrict__ b_ids, const int* __restrict__ i_ids,
    const int* __restrict__ j_ids, const int* __restrict__ w0c_p,
    const int* __restrict__ w1c_p, const float* __restrict__ ctxs,
    const float* __restrict__ bias_all, const bf16_t* __restrict__ A_swz,
    const bf16_t* __restrict__ DmB, float* __restrict__ out) {
  __shared__ __align__(16) bf16_t sV[3][32][PAD];
  __shared__ float sg[2][128];
  int n = blockIdx.x;
  int tid = threadIdx.x;
  int b = b_ids[n], ii = i_ids[n], jj = j_ids[n];
  int w0c = w0c_p[0], w1c = w1c_p[0];
  int x0 = min((ii % w0c) * 2, WF - 1), y0 = min((ii / w0c) * 2, HF - 1);
  int x1 = min((jj % w1c) * 2, WF - 1), y1 = min((jj / w1c) * 2, HF - 1);
  const float ksc = INV_S / (float)HW;
  int c = tid & 127, kh = tid >> 7;
  float cs0 = ctxs[b * 128 + c] * ksc;
  float cs1 = ctxs[256 + b * 128 + c] * ksc;
  const float* f0b = f0 + (size_t)(b * 128 + c) * HW;
  const float* f1b = f1 + (size_t)(b * 128 + c) * HW;
  for (int k = kh; k < 32; k += 2) {
    float p0 = 0.f, p1 = 0.f;
    if (k < 25) {
      int dy = k / 5 - 2, dx = k % 5 - 2;
      int ya = y0 + dy, xa = x0 + dx;
      if (ya >= 0 && ya < HF && xa >= 0 && xa < WF) p0 = f0b[ya * WF + xa];
      int yb = y1 + dy, xb = x1 + dx;
      if (yb >= 0 && yb < HF && xb >= 0 && xb < WF) p1 = f1b[yb * WF + xb];
    }
    sV[0][k][c] = (bf16_t)(p0 * p1);
    sV[1][k][c] = (bf16_t)(p0 * cs1);
    sV[2][k][c] = (bf16_t)(p1 * cs0);
  }
  {
    int h = tid >> 7, col = tid & 127;
    const float* fcrow = h ? fc1 + ((size_t)b * LC + jj) * D_C
                           : fc0 + ((size_t)b * LC + ii) * D_C;
    const bf16_t* dbase = DmB + col * 8;
    float p0 = 0.f, p1 = 0.f, p2 = 0.f, p3 = 0.f;
#pragma unroll 4
    for (int t8 = 0; t8 < 32; ++t8) {
      bf16x8 d  = *(const bf16x8*)(dbase + t8 * 1024);
      f32x4  fa = *(const f32x4*)(fcrow + t8 * 8);
      f32x4  fb = *(const f32x4*)(fcrow + t8 * 8 + 4);
      p0 += fa[0] * (float)d[0] + fb[0] * (float)d[4];
      p1 += fa[1] * (float)d[1] + fb[1] * (float)d[5];
      p2 += fa[2] * (float)d[2] + fb[2] * (float)d[6];
      p3 += fa[3] * (float)d[3] + fb[3] * (float)d[7];
    }
    sg[h][col] = ((p0 + p1) + (p2 + p3));
  }
  __syncthreads();
  int w = tid >> 6, lane = tid & 63, quad = lane >> 4, lr = lane & 15;
  f32x4 accP[2][2] = {}, acc01[2][2] = {}, acc10[2][2] = {};
#pragma unroll
  for (int ks = 0; ks < 4; ++ks) {
    bf16x8 va[2][3];
#pragma unroll
    for (int mt = 0; mt < 2; ++mt)
#pragma unroll
      for (int m = 0; m < 3; ++m)
        va[mt][m] = *(const bf16x8*)&sV[m][mt * 16 + lr][ks * 32 + quad * 8];
    bf16x8 vb[3][2];
#pragma unroll
    for (int m = 0; m < 3; ++m)
#pragma unroll
      for (int ntl = 0; ntl < 2; ++ntl) {
        int nt = w * 2 + ntl;
        vb[m][ntl] = *(const bf16x8*)(A_swz + m * 16384 + (((nt * 4 + ks) * 64) + lane) * 8);
      }
#pragma unroll
    for (int mt = 0; mt < 2; ++mt)
#pragma unroll
      for (int ntl = 0; ntl < 2; ++ntl) {
        accP[mt][ntl]  = __builtin_amdgcn_mfma_f32_16x16x32_bf16(va[mt][0], vb[0][ntl], accP[mt][ntl], 0, 0, 0);
        acc01[mt][ntl] = __builtin_amdgcn_mfma_f32_16x16x32_bf16(va[mt][1], vb[1][ntl], acc01[mt][ntl], 0, 0, 0);
        acc01[mt][ntl] = __builtin_amdgcn_mfma_f32_16x16x32_bf16(va[mt][2], vb[2][ntl], acc01[mt][ntl], 0, 0, 0);
        acc10[mt][ntl] = __builtin_amdgcn_mfma_f32_16x16x32_bf16(va[mt][2], vb[1][ntl], acc10[mt][ntl], 0, 0, 0);
        acc10[mt][ntl] = __builtin_amdgcn_mfma_f32_16x16x32_bf16(va[mt][1], vb[2][ntl], acc10[mt][ntl], 0, 0, 0);
      }
  }
#pragma unroll
  for (int ntl = 0; ntl < 2; ++ntl) {
    int col = w * 32 + ntl * 16 + lr;
    float bg = bias_all[col];
    float gg0 = sg[0][col] + bg, gg1 = sg[1][col] + bg;
#pragma unroll
    for (int mt = 0; mt < 2; ++mt)
#pragma unroll
      for (int rg = 0; rg < 4; ++rg) {
        int row = mt * 16 + quad * 4 + rg;
        if (row < 25) {
          size_t o = ((size_t)n * 25 + row) * 128 + col;
          out[o] = accP[mt][ntl][rg] + acc01[mt][ntl][rg] + gg0;
          out[(size_t)NPTS * 25 * 128 + o] = accP[mt][ntl][rg] + acc10[mt][ntl][rg] + gg1;
        }
      }
  }
}

// ---------------------------------------------------------------------------
extern "C" void kernel_launch(void* const* d_in, const int* in_sizes, int n_in,
                              void* d_out, int out_size, void* d_ws, size_t ws_size,
                              hipStream_t stream) {
  const float* f0     = (const float*)d_in[0];
  const float* f1     = (const float*)d_in[1];
  const float* fc0    = (const float*)d_in[2];
  const float* fc1    = (const float*)d_in[3];
  const float* corr_w = (const float*)d_in[4];
  const float* corr_b = (const float*)d_in[5];
  const float* dp_w   = (const float*)d_in[6];
  const float* dp_b   = (const float*)d_in[7];
  const float* mg_w   = (const float*)d_in[8];
  const float* mg_b   = (const float*)d_in[9];
  const int* b_ids    = (const int*)d_in[10];
  const int* i_ids    = (const int*)d_in[11];
  const int* j_ids    = (const int*)d_in[12];
  const int* w0c      = (const int*)d_in[13];
  const int* w1c      = (const int*)d_in[14];

  char* ws = (char*)d_ws;
  float*  ctxs     = (float*)(ws);
  float*  bias_all = (float*)(ws + 4096);
  bf16_t* A_swz    = (bf16_t*)(ws + 8192);
  bf16_t* DmB      = (bf16_t*)(ws + 106496);
  bf16_t* ftr      = (bf16_t*)(ws + FTR_OFF);
  float*  g        = (float*)(ws + G_OFF);
  int fast = (ws_size >= G_OFF + G_BYTES) ? 1 : 0;

  if (fast) {
    hipMemsetAsync(ctxs, 0, 2048, stream);
    // g (625) + prep (641) + transpose (2704) fused: one dispatch, all
    // three parts independent (g stores raw fc@dp@mg2; bias added in main).
    ptg_kernel<<<PTG_GRID, 256, 0, stream>>>(
        f0, f1, fc0, fc1, corr_w, corr_b, dp_w, dp_b, mg_w, mg_b,
        b_ids, i_ids, j_ids, A_swz, DmB, bias_all, ftr, ctxs, g);
    main_kernel<<<NPTS, 256, 0, stream>>>(ftr, b_ids, i_ids, j_ids, w0c, w1c,
                                          ctxs, A_swz, g, bias_all,
                                          (float*)d_out);
  } else {
    // prep-only dispatch (grid==641 -> every block runs the prep role)
    ptg_kernel<<<641, 256, 0, stream>>>(
        f0, f1, fc0, fc1, corr_w, corr_b, dp_w, dp_b, mg_w, mg_b,
        b_ids, i_ids, j_ids, A_swz, DmB, bias_all, ftr, ctxs, g);
    ctx_mean_f32_kernel<<<512, 256, 0, stream>>>(f0, f1, ctxs);
    main_fallback_kernel<<<NPTS, 256, 0, stream>>>(f0, f1, fc0, fc1, b_ids,
                                                   i_ids, j_ids, w0c, w1c, ctxs,
                                                   bias_all, A_swz, DmB,
                                                   (float*)d_out);
  }
}